// Round 2
// baseline (510.279 us; speedup 1.0000x reference)
//
#include <hip/hip_runtime.h>
#include <hip/hip_bf16.h>
#include <math.h>

#define NUM_CLASSES 81
#define TOP_K       200
#define NBINS       4096
#define CAND_MAX    1024
#define NSORT       1024
#define CONF_THRESH 0.05f
#define NMS_THRESH  0.45f
// Fast-path collection threshold: 4055/4096 (exactly representable in f32).
// E[count above] = 65536*(1-4055/4096) ~= 656 per column, sigma ~= 25.
#define T0F (4055.0f / 4096.0f)

// ---------------------------------------------------------------------------
// Kernel 1: coalesced pass over conf, scatter candidates to ws buckets.
// conf flat index e = (b*A + a)*81 + c  ->  bucket bc = b*81 + c.
// ---------------------------------------------------------------------------
__global__ __launch_bounds__(256) void collect_kernel(
    const float4* __restrict__ conf4,
    unsigned long long* __restrict__ cand,   // [648][CAND_MAX]
    int* __restrict__ counts,                // [648]
    unsigned AC,                             // A * 81
    unsigned N4)                             // total floats / 4
{
    unsigned stride = gridDim.x * blockDim.x;
    for (unsigned t = blockIdx.x * blockDim.x + threadIdx.x; t < N4; t += stride) {
        float4 v4 = conf4[t];
        float vs[4] = {v4.x, v4.y, v4.z, v4.w};
#pragma unroll
        for (int j = 0; j < 4; ++j) {
            float v = vs[j];
            if (v > T0F) {                       // ~1% of elements
                unsigned e   = 4u * t + (unsigned)j;
                unsigned b   = e / AC;
                unsigned rem = e - b * AC;
                unsigned a   = rem / NUM_CLASSES;
                unsigned c   = rem - a * NUM_CLASSES;
                unsigned bc  = b * NUM_CLASSES + c;
                int pos = atomicAdd(&counts[bc], 1);
                if (pos < CAND_MAX)
                    cand[(size_t)bc * CAND_MAX + pos] =
                        ((unsigned long long)__float_as_uint(v) << 32) |
                        (unsigned)(~a);
            }
        }
    }
}

// ---------------------------------------------------------------------------
// Kernel 2: per-(b,c) finalize: sort candidates, decode, bitmask NMS, write.
// ---------------------------------------------------------------------------
__global__ __launch_bounds__(256) void finalize_kernel(
    const float* __restrict__ loc,      // [B, A, 4]
    const float* __restrict__ conf,     // [B, A*81] (fallback path only)
    const float* __restrict__ anchors,  // [A, 4]
    const unsigned long long* __restrict__ cand,
    const int* __restrict__ counts,
    float* __restrict__ out,
    int A, int use_ws)
{
    __shared__ unsigned long long sk[NSORT];       // 8 KB
    __shared__ unsigned s_scratch[NBINS];          // 16 KB, multi-purpose
    __shared__ int s_cnt;
    __shared__ int s_tbin;

    // phase-1 alias: histogram (fallback only)
    int* hist = (int*)s_scratch;
    // phase-2 aliases (after sort):
    unsigned (*sup)[8] = (unsigned(*)[8])s_scratch;        // [200][8] = 1600 u32
    float* bx0 = (float*)(s_scratch + 1600);
    float* by0 = (float*)(s_scratch + 1800);
    float* bx1 = (float*)(s_scratch + 2000);
    float* by1 = (float*)(s_scratch + 2200);
    float* bar = (float*)(s_scratch + 2400);
    float* bsc = (float*)(s_scratch + 2600);
    unsigned* s_keep = s_scratch + 2800;                    // [8]

    const int tid = threadIdx.x;
    const int bc  = blockIdx.x;
    const int b   = bc / NUM_CLASSES;
    const int c   = bc % NUM_CLASSES;

    // ---- Get candidates into sk[0..cnt) ----
    int cnt = -1;
    if (use_ws) {
        cnt = counts[bc];
        if (cnt >= TOP_K && cnt <= CAND_MAX) {
            for (int i = tid; i < cnt; i += 256)
                sk[i] = cand[(size_t)bc * CAND_MAX + i];
        } else {
            cnt = -1;  // trigger fallback
        }
    }

    if (cnt < 0) {
        // ---- Fallback: strided scan (+ exact histogram select if needed) ----
        const float* cp = conf + (size_t)b * A * NUM_CLASSES + c;
        if (tid == 0) s_cnt = 0;
        __syncthreads();
        for (int a = tid; a < A; a += 256) {
            float v = cp[(size_t)a * NUM_CLASSES];
            if (v > T0F) {
                int pos = atomicAdd(&s_cnt, 1);
                if (pos < CAND_MAX)
                    sk[pos] = ((unsigned long long)__float_as_uint(v) << 32) |
                              (unsigned)(~(unsigned)a);
            }
        }
        __syncthreads();
        cnt = s_cnt;
        if (cnt < TOP_K || cnt > CAND_MAX) {
            for (int i = tid; i < NBINS; i += 256) hist[i] = 0;
            __syncthreads();
            for (int a = tid; a < A; a += 256) {
                float v = cp[(size_t)a * NUM_CLASSES];
                if (v > CONF_THRESH) {
                    int bin = (int)(v * (float)NBINS);
                    bin = bin < 0 ? 0 : (bin > NBINS - 1 ? NBINS - 1 : bin);
                    atomicAdd(&hist[bin], 1);
                }
            }
            __syncthreads();
            if (tid == 0) {
                int acc = 0, t = NBINS - 1;
                for (; t > 0; --t) { acc += hist[t]; if (acc >= TOP_K) break; }
                s_tbin = t;
                s_cnt  = 0;
            }
            __syncthreads();
            int tb = s_tbin;
            for (int a = tid; a < A; a += 256) {
                float v = cp[(size_t)a * NUM_CLASSES];
                if (v > CONF_THRESH) {
                    int bin = (int)(v * (float)NBINS);
                    bin = bin < 0 ? 0 : (bin > NBINS - 1 ? NBINS - 1 : bin);
                    if (bin >= tb) {
                        int pos = atomicAdd(&s_cnt, 1);
                        if (pos < CAND_MAX)
                            sk[pos] = ((unsigned long long)__float_as_uint(v) << 32) |
                                      (unsigned)(~(unsigned)a);
                    }
                }
            }
            __syncthreads();
            cnt = s_cnt < CAND_MAX ? s_cnt : CAND_MAX;
        }
    }
    __syncthreads();

    // ---- Pad and bitonic-sort descending (key = (score_bits, ~idx)) ----
    for (int i = cnt + tid; i < NSORT; i += 256) sk[i] = 0ULL;
    __syncthreads();

    for (int k = 2; k <= NSORT; k <<= 1) {
        for (int j = k >> 1; j > 0; j >>= 1) {
            for (int i = tid; i < NSORT; i += 256) {
                int ixj = i ^ j;
                if (ixj > i) {
                    unsigned long long va = sk[i], vb = sk[ixj];
                    bool up = (i & k) == 0;  // descending network
                    if (up ? (va < vb) : (va > vb)) { sk[i] = vb; sk[ixj] = va; }
                }
            }
            __syncthreads();
        }
    }

    // ---- Decode top-200 (f32 ops in reference order; no FMA contraction),
    //      and zero the sup/keep region in parallel ----
    for (int i = tid; i < 1600; i += 256) s_scratch[i] = 0;   // sup
    if (tid < 16) s_keep[tid & 7] = 0;                        // keep words
    if (tid < TOP_K) {
        unsigned long long key = sk[tid];
        float sc = 0.f, x0 = 0.f, y0 = 0.f, x1 = 0.f, y1 = 0.f;
        if (key != 0ULL) {
            sc = __uint_as_float((unsigned)(key >> 32));
            unsigned idx = ~(unsigned)(key & 0xFFFFFFFFu);
            const float* lp = loc + ((size_t)b * A + idx) * 4;
            const float* ap = anchors + (size_t)idx * 4;
            float l0 = lp[0], l1 = lp[1], l2 = lp[2], l3 = lp[3];
            float acx = ap[0], acy = ap[1], aw = ap[2], ah = ap[3];
            float cx = __fadd_rn(acx, __fmul_rn(__fmul_rn(l0, 0.1f), aw));
            float cy = __fadd_rn(acy, __fmul_rn(__fmul_rn(l1, 0.1f), ah));
            float ew = (float)exp((double)__fmul_rn(l2, 0.2f));
            float eh = (float)exp((double)__fmul_rn(l3, 0.2f));
            float w  = __fmul_rn(aw, ew);
            float h  = __fmul_rn(ah, eh);
            float hw = __fmul_rn(w, 0.5f), hh = __fmul_rn(h, 0.5f);
            x0 = __fsub_rn(cx, hw); y0 = __fsub_rn(cy, hh);
            x1 = __fadd_rn(cx, hw); y1 = __fadd_rn(cy, hh);
        }
        bx0[tid] = x0; by0[tid] = y0; bx1[tid] = x1; by1[tid] = y1;
        bar[tid] = __fmul_rn(__fsub_rn(x1, x0), __fsub_rn(y1, y0));
        bsc[tid] = sc;
    }
    __syncthreads();

    // ---- Build suppression bitmask: sup[i] bit j set iff iou(i,j)>thr, j>i ----
    if (tid < TOP_K && bsc[tid] > CONF_THRESH)
        atomicOr(&s_keep[tid >> 5], 1u << (tid & 31));
    for (int i = 0; i < TOP_K - 1; ++i) {
        int j = i + 1 + tid;
        if (j < TOP_K) {
            float ltx = fmaxf(bx0[i], bx0[j]);
            float lty = fmaxf(by0[i], by0[j]);
            float rbx = fminf(bx1[i], bx1[j]);
            float rby = fminf(by1[i], by1[j]);
            float iw  = fmaxf(__fsub_rn(rbx, ltx), 0.f);
            float ih  = fmaxf(__fsub_rn(rby, lty), 0.f);
            float inter = __fmul_rn(iw, ih);
            float denom = __fadd_rn(
                __fsub_rn(__fadd_rn(bar[i], bar[j]), inter), 1e-9f);
            float iou = __fdiv_rn(inter, denom);
            if (iou > NMS_THRESH) atomicOr(&sup[i][j >> 5], 1u << (j & 31));
        }
    }
    __syncthreads();

    // ---- Sequential keep propagation on wave 0 (bit ops, no barriers) ----
    if (tid < 64) {
        unsigned keepw = (tid < 7) ? s_keep[tid] : 0u;
        for (int i = 0; i < TOP_K; ++i) {
            unsigned kw = __shfl(keepw, i >> 5, 64);
            if ((kw >> (i & 31)) & 1u) {
                if (tid < 7) keepw &= ~sup[i][tid];
            }
        }
        if (tid < 7) s_keep[tid] = keepw;
    }
    __syncthreads();

    // ---- Write outputs ----
    if (tid < TOP_K) {
        int kp = (s_keep[tid >> 5] >> (tid & 31)) & 1u;
        size_t lb = ((size_t)bc * TOP_K + tid) * 4;
        out[lb + 0] = kp ? bx0[tid] : 0.f;
        out[lb + 1] = kp ? by0[tid] : 0.f;
        out[lb + 2] = kp ? bx1[tid] : 0.f;
        out[lb + 3] = kp ? by1[tid] : 0.f;
        out[(size_t)gridDim.x * TOP_K * 4 + (size_t)bc * TOP_K + tid] =
            kp ? bsc[tid] : 0.f;
    }
}

extern "C" void kernel_launch(void* const* d_in, const int* in_sizes, int n_in,
                              void* d_out, int out_size, void* d_ws, size_t ws_size,
                              hipStream_t stream) {
    const float* loc     = (const float*)d_in[0];
    const float* conf    = (const float*)d_in[1];
    const float* anchors = (const float*)d_in[2];
    float* out = (float*)d_out;

    int A = in_sizes[2] / 4;                 // anchors: [A,4]
    int B = in_sizes[0] / (A * 4);           // preds_loc: [B,A,4]
    int BC = B * NUM_CLASSES;

    size_t counts_bytes = 8192;  // counts padded to 8 KB for cand alignment
    size_t need = counts_bytes + (size_t)BC * CAND_MAX * sizeof(unsigned long long);
    int use_ws = (ws_size >= need) ? 1 : 0;

    int* counts = (int*)d_ws;
    unsigned long long* cand = (unsigned long long*)((char*)d_ws + counts_bytes);

    if (use_ws) {
        hipMemsetAsync(counts, 0, (size_t)BC * sizeof(int), stream);
        unsigned AC = (unsigned)A * NUM_CLASSES;
        unsigned N4 = (unsigned)B * AC / 4u;
        collect_kernel<<<4096, 256, 0, stream>>>(
            (const float4*)conf, cand, counts, AC, N4);
    }

    finalize_kernel<<<BC, 256, 0, stream>>>(
        loc, conf, anchors, cand, counts, out, A, use_ws);
}

// Round 3
// 150.175 us; speedup vs baseline: 3.3979x; 3.3979x over previous
//
#include <hip/hip_runtime.h>
#include <hip/hip_bf16.h>
#include <math.h>

#define NUM_CLASSES 81
#define TOP_K       200
#define NBINS       4096
#define CAND_MAX    1024
#define NSORT       1024
#define CONF_THRESH 0.05f
#define NMS_THRESH  0.45f
// Fast-path collection threshold: 4055/4096 (exactly representable in f32).
// E[count above] = 65536*(1-4055/4096) ~= 656 per column, sigma ~= 25.
#define T0F (4055.0f / 4096.0f)

// ---------------------------------------------------------------------------
// Kernel 1: coalesced pass over conf, scatter candidates to ws buckets.
// conf flat index e = (b*A + a)*81 + c  ->  bucket bc = b*81 + c.
// counts[bc * cstride]: cstride=16 puts each counter on its own 64B line
// (R2 post-mortem: 16 counters/line false-shared -> ~10K serialized RMWs/line).
// ---------------------------------------------------------------------------
__global__ __launch_bounds__(256) void collect_kernel(
    const float4* __restrict__ conf4,
    unsigned long long* __restrict__ cand,   // [648][CAND_MAX]
    int* __restrict__ counts,                // [648 * cstride]
    unsigned AC,                             // A * 81
    unsigned N4,                             // total floats / 4
    int cstride)
{
    unsigned stride = gridDim.x * blockDim.x;
    for (unsigned t = blockIdx.x * blockDim.x + threadIdx.x; t < N4; t += stride) {
        float4 v4 = conf4[t];
        float vs[4] = {v4.x, v4.y, v4.z, v4.w};
#pragma unroll
        for (int j = 0; j < 4; ++j) {
            float v = vs[j];
            if (v > T0F) {                       // ~1% of elements
                unsigned e   = 4u * t + (unsigned)j;
                unsigned b   = e / AC;
                unsigned rem = e - b * AC;
                unsigned a   = rem / NUM_CLASSES;
                unsigned c   = rem - a * NUM_CLASSES;
                unsigned bc  = b * NUM_CLASSES + c;
                int pos = atomicAdd(&counts[bc * cstride], 1);
                if (pos < CAND_MAX)
                    cand[(size_t)bc * CAND_MAX + pos] =
                        ((unsigned long long)__float_as_uint(v) << 32) |
                        (unsigned)(~a);
            }
        }
    }
}

// ---------------------------------------------------------------------------
// Kernel 2: per-(b,c) finalize: sort candidates, decode, bitmask NMS, write.
// ---------------------------------------------------------------------------
__global__ __launch_bounds__(256) void finalize_kernel(
    const float* __restrict__ loc,      // [B, A, 4]
    const float* __restrict__ conf,     // [B, A*81] (fallback path only)
    const float* __restrict__ anchors,  // [A, 4]
    const unsigned long long* __restrict__ cand,
    const int* __restrict__ counts,
    float* __restrict__ out,
    int A, int use_ws, int cstride)
{
    __shared__ unsigned long long sk[NSORT];       // 8 KB
    __shared__ unsigned s_scratch[NBINS];          // 16 KB, multi-purpose
    __shared__ int s_cnt;
    __shared__ int s_tbin;

    // phase-1 alias: histogram (fallback only)
    int* hist = (int*)s_scratch;
    // phase-2 aliases (after sort):
    unsigned (*sup)[8] = (unsigned(*)[8])s_scratch;        // [200][8] = 1600 u32
    float* bx0 = (float*)(s_scratch + 1600);
    float* by0 = (float*)(s_scratch + 1800);
    float* bx1 = (float*)(s_scratch + 2000);
    float* by1 = (float*)(s_scratch + 2200);
    float* bar = (float*)(s_scratch + 2400);
    float* bsc = (float*)(s_scratch + 2600);
    unsigned* s_keep = s_scratch + 2800;                    // [8]

    const int tid = threadIdx.x;
    const int bc  = blockIdx.x;
    const int b   = bc / NUM_CLASSES;
    const int c   = bc % NUM_CLASSES;

    // ---- Get candidates into sk[0..cnt) ----
    int cnt = -1;
    if (use_ws) {
        cnt = counts[bc * cstride];
        if (cnt >= TOP_K && cnt <= CAND_MAX) {
            for (int i = tid; i < cnt; i += 256)
                sk[i] = cand[(size_t)bc * CAND_MAX + i];
        } else {
            cnt = -1;  // trigger fallback
        }
    }

    if (cnt < 0) {
        // ---- Fallback: strided scan (+ exact histogram select if needed) ----
        const float* cp = conf + (size_t)b * A * NUM_CLASSES + c;
        if (tid == 0) s_cnt = 0;
        __syncthreads();
        for (int a = tid; a < A; a += 256) {
            float v = cp[(size_t)a * NUM_CLASSES];
            if (v > T0F) {
                int pos = atomicAdd(&s_cnt, 1);
                if (pos < CAND_MAX)
                    sk[pos] = ((unsigned long long)__float_as_uint(v) << 32) |
                              (unsigned)(~(unsigned)a);
            }
        }
        __syncthreads();
        cnt = s_cnt;
        if (cnt < TOP_K || cnt > CAND_MAX) {
            for (int i = tid; i < NBINS; i += 256) hist[i] = 0;
            __syncthreads();
            for (int a = tid; a < A; a += 256) {
                float v = cp[(size_t)a * NUM_CLASSES];
                if (v > CONF_THRESH) {
                    int bin = (int)(v * (float)NBINS);
                    bin = bin < 0 ? 0 : (bin > NBINS - 1 ? NBINS - 1 : bin);
                    atomicAdd(&hist[bin], 1);
                }
            }
            __syncthreads();
            if (tid == 0) {
                int acc = 0, t = NBINS - 1;
                for (; t > 0; --t) { acc += hist[t]; if (acc >= TOP_K) break; }
                s_tbin = t;
                s_cnt  = 0;
            }
            __syncthreads();
            int tb = s_tbin;
            for (int a = tid; a < A; a += 256) {
                float v = cp[(size_t)a * NUM_CLASSES];
                if (v > CONF_THRESH) {
                    int bin = (int)(v * (float)NBINS);
                    bin = bin < 0 ? 0 : (bin > NBINS - 1 ? NBINS - 1 : bin);
                    if (bin >= tb) {
                        int pos = atomicAdd(&s_cnt, 1);
                        if (pos < CAND_MAX)
                            sk[pos] = ((unsigned long long)__float_as_uint(v) << 32) |
                                      (unsigned)(~(unsigned)a);
                    }
                }
            }
            __syncthreads();
            cnt = s_cnt < CAND_MAX ? s_cnt : CAND_MAX;
        }
    }
    __syncthreads();

    // ---- Pad and bitonic-sort descending (key = (score_bits, ~idx)) ----
    for (int i = cnt + tid; i < NSORT; i += 256) sk[i] = 0ULL;
    __syncthreads();

    for (int k = 2; k <= NSORT; k <<= 1) {
        for (int j = k >> 1; j > 0; j >>= 1) {
            for (int i = tid; i < NSORT; i += 256) {
                int ixj = i ^ j;
                if (ixj > i) {
                    unsigned long long va = sk[i], vb = sk[ixj];
                    bool up = (i & k) == 0;  // descending network
                    if (up ? (va < vb) : (va > vb)) { sk[i] = vb; sk[ixj] = va; }
                }
            }
            __syncthreads();
        }
    }

    // ---- Decode top-200 (f32 ops in reference order; no FMA contraction),
    //      and zero the sup/keep region in parallel ----
    for (int i = tid; i < 1600; i += 256) s_scratch[i] = 0;   // sup
    if (tid < 8) s_keep[tid] = 0;
    if (tid < TOP_K) {
        unsigned long long key = sk[tid];
        float sc = 0.f, x0 = 0.f, y0 = 0.f, x1 = 0.f, y1 = 0.f;
        if (key != 0ULL) {
            sc = __uint_as_float((unsigned)(key >> 32));
            unsigned idx = ~(unsigned)(key & 0xFFFFFFFFu);
            const float* lp = loc + ((size_t)b * A + idx) * 4;
            const float* ap = anchors + (size_t)idx * 4;
            float l0 = lp[0], l1 = lp[1], l2 = lp[2], l3 = lp[3];
            float acx = ap[0], acy = ap[1], aw = ap[2], ah = ap[3];
            float cx = __fadd_rn(acx, __fmul_rn(__fmul_rn(l0, 0.1f), aw));
            float cy = __fadd_rn(acy, __fmul_rn(__fmul_rn(l1, 0.1f), ah));
            float ew = (float)exp((double)__fmul_rn(l2, 0.2f));
            float eh = (float)exp((double)__fmul_rn(l3, 0.2f));
            float w  = __fmul_rn(aw, ew);
            float h  = __fmul_rn(ah, eh);
            float hw = __fmul_rn(w, 0.5f), hh = __fmul_rn(h, 0.5f);
            x0 = __fsub_rn(cx, hw); y0 = __fsub_rn(cy, hh);
            x1 = __fadd_rn(cx, hw); y1 = __fadd_rn(cy, hh);
        }
        bx0[tid] = x0; by0[tid] = y0; bx1[tid] = x1; by1[tid] = y1;
        bar[tid] = __fmul_rn(__fsub_rn(x1, x0), __fsub_rn(y1, y0));
        bsc[tid] = sc;
    }
    __syncthreads();

    // ---- Build suppression bitmask, barrier-free per-wave row partition:
    //      sup[i] bit j set iff iou(i,j)>thr, j>i ----
    if (tid < TOP_K && bsc[tid] > CONF_THRESH)
        atomicOr(&s_keep[tid >> 5], 1u << (tid & 31));
    {
        const int wave = tid >> 6, lane = tid & 63;
        for (int i = wave; i < TOP_K - 1; i += 4) {
            float ix0 = bx0[i], iy0 = by0[i], ix1 = bx1[i], iy1 = by1[i];
            float iar = bar[i];
            for (int j = i + 1 + lane; j < TOP_K; j += 64) {
                float ltx = fmaxf(ix0, bx0[j]);
                float lty = fmaxf(iy0, by0[j]);
                float rbx = fminf(ix1, bx1[j]);
                float rby = fminf(iy1, by1[j]);
                float iw  = fmaxf(__fsub_rn(rbx, ltx), 0.f);
                float ih  = fmaxf(__fsub_rn(rby, lty), 0.f);
                float inter = __fmul_rn(iw, ih);
                float denom = __fadd_rn(
                    __fsub_rn(__fadd_rn(iar, bar[j]), inter), 1e-9f);
                float iou = __fdiv_rn(inter, denom);
                if (iou > NMS_THRESH) atomicOr(&sup[i][j >> 5], 1u << (j & 31));
            }
        }
    }
    __syncthreads();

    // ---- Sequential keep propagation on wave 0 (bit ops, no barriers) ----
    if (tid < 64) {
        unsigned keepw = (tid < 7) ? s_keep[tid] : 0u;
        for (int i = 0; i < TOP_K; ++i) {
            unsigned kw = __shfl(keepw, i >> 5, 64);
            if ((kw >> (i & 31)) & 1u) {
                if (tid < 7) keepw &= ~sup[i][tid];
            }
        }
        if (tid < 7) s_keep[tid] = keepw;
    }
    __syncthreads();

    // ---- Write outputs ----
    if (tid < TOP_K) {
        int kp = (s_keep[tid >> 5] >> (tid & 31)) & 1u;
        size_t lb = ((size_t)bc * TOP_K + tid) * 4;
        out[lb + 0] = kp ? bx0[tid] : 0.f;
        out[lb + 1] = kp ? by0[tid] : 0.f;
        out[lb + 2] = kp ? bx1[tid] : 0.f;
        out[lb + 3] = kp ? by1[tid] : 0.f;
        out[(size_t)gridDim.x * TOP_K * 4 + (size_t)bc * TOP_K + tid] =
            kp ? bsc[tid] : 0.f;
    }
}

extern "C" void kernel_launch(void* const* d_in, const int* in_sizes, int n_in,
                              void* d_out, int out_size, void* d_ws, size_t ws_size,
                              hipStream_t stream) {
    const float* loc     = (const float*)d_in[0];
    const float* conf    = (const float*)d_in[1];
    const float* anchors = (const float*)d_in[2];
    float* out = (float*)d_out;

    int A = in_sizes[2] / 4;                 // anchors: [A,4]
    int B = in_sizes[0] / (A * 4);           // preds_loc: [B,A,4]
    int BC = B * NUM_CLASSES;

    // Prefer one 64B cache line per counter (cstride=16) to kill atomic
    // false-sharing; fall back to packed counters, then to no-ws path.
    size_t cand_bytes = (size_t)BC * CAND_MAX * sizeof(unsigned long long);
    int cstride, use_ws;
    size_t counts_bytes;
    if (ws_size >= 65536 + cand_bytes) {
        cstride = 16; counts_bytes = 65536; use_ws = 1;
    } else if (ws_size >= 8192 + cand_bytes) {
        cstride = 1;  counts_bytes = 8192;  use_ws = 1;
    } else {
        cstride = 1;  counts_bytes = 0;     use_ws = 0;
    }

    int* counts = (int*)d_ws;
    unsigned long long* cand = (unsigned long long*)((char*)d_ws + counts_bytes);

    if (use_ws) {
        hipMemsetAsync(counts, 0, (size_t)BC * cstride * sizeof(int), stream);
        unsigned AC = (unsigned)A * NUM_CLASSES;
        unsigned N4 = (unsigned)B * AC / 4u;
        collect_kernel<<<4096, 256, 0, stream>>>(
            (const float4*)conf, cand, counts, AC, N4, cstride);
    }

    finalize_kernel<<<BC, 256, 0, stream>>>(
        loc, conf, anchors, cand, counts, out, A, use_ws, cstride);
}